// Round 1
// 2629.601 us; speedup vs baseline: 1.0182x; 1.0182x over previous
//
#include <hip/hip_runtime.h>
#include <math.h>

#define N_NODES 50000
#define N_EDGES 800000
#define HDIM 128
#define EPSV 1e-8f

__device__ __forceinline__ float silu_(float x){ return x / (1.0f + __expf(-x)); }
__device__ __forceinline__ float clip100(float x){ return fminf(fmaxf(x, -100.0f), 100.0f); }

__device__ __forceinline__ void fma8x4(float (&acc)[8][4], const float4& a0, const float4& a1, const float4& w){
    float av[8] = {a0.x,a0.y,a0.z,a0.w,a1.x,a1.y,a1.z,a1.w};
    float wv[4] = {w.x,w.y,w.z,w.w};
#pragma unroll
    for(int r=0;r<8;r++)
#pragma unroll
        for(int c=0;c<4;c++) acc[r][c] += av[r]*wv[c];
}

// ---------------- CSR build ----------------
__global__ void count_kernel(const int* __restrict__ senders, int* __restrict__ cursor){
    int e = blockIdx.x*256 + threadIdx.x;
    if(e < N_EDGES) atomicAdd(&cursor[senders[e]], 1);
}

__global__ __launch_bounds__(1024) void scan_kernel(int* __restrict__ cursor, int* __restrict__ offs){
    __shared__ int lds[1024];
    const int CH = 49;                      // 1024*49 >= 50000
    int t = threadIdx.x;
    int base = t*CH;
    int sum = 0;
    for(int i=0;i<CH;i++){ int idx = base+i; if(idx < N_NODES) sum += cursor[idx]; }
    lds[t] = sum; __syncthreads();
    for(int off=1; off<1024; off<<=1){
        int v = (t>=off)? lds[t-off] : 0;
        __syncthreads();
        lds[t] += v;
        __syncthreads();
    }
    int run = lds[t] - sum;                 // exclusive prefix
    for(int i=0;i<CH;i++){
        int idx = base+i;
        if(idx < N_NODES){
            int c = cursor[idx];
            offs[idx] = run;
            cursor[idx] = run;              // scatter cursor
            run += c;
        }
    }
    if(t==1023) offs[N_NODES] = lds[1023];
}

__global__ void scatter_kernel(const int* __restrict__ senders, int* __restrict__ cursor, int* __restrict__ eord){
    int e = blockIdx.x*256 + threadIdx.x;
    if(e < N_EDGES){
        int pos = atomicAdd(&cursor[senders[e]], 1);
        eord[pos] = e;
    }
}

// ---------------- x = silu(s@W1+b1)@W2+b2 ----------------
// 64 nodes/block, 256 threads. LDS: sT[128][68] overlaid by hT[128][68]. 34.8KB.
__global__ __launch_bounds__(256) void mlp_x_kernel(
    const float* __restrict__ s, const float* __restrict__ W1, const float* __restrict__ b1,
    const float* __restrict__ W2, const float* __restrict__ b2, float* __restrict__ x)
{
    __shared__ float smem[128*68];
    int t = threadIdx.x, tx = t&31, ty = t>>5;
    int n0 = blockIdx.x*64;
    int col = tx*4;

    for(int f=t; f<64*128; f+=256){
        int i = f>>7, k = f&127;
        int n = n0+i;
        smem[k*68+i] = (n<N_NODES)? s[(size_t)n*128+k] : 0.0f;
    }
    __syncthreads();

    float acc[8][4];
    { float4 b = *(const float4*)&b1[col];
#pragma unroll
      for(int r=0;r<8;r++){acc[r][0]=b.x;acc[r][1]=b.y;acc[r][2]=b.z;acc[r][3]=b.w;} }
    for(int k=0;k<128;k++){
        float4 w  = *(const float4*)&W1[k*128+col];
        float4 a0 = *(const float4*)&smem[k*68 + ty*8];
        float4 a1 = *(const float4*)&smem[k*68 + ty*8 + 4];
        fma8x4(acc, a0, a1, w);
    }
    __syncthreads();   // all sT reads done
#pragma unroll
    for(int c=0;c<4;c++)
#pragma unroll
        for(int r=0;r<8;r++) smem[(col+c)*68 + ty*8 + r] = silu_(acc[r][c]);
    __syncthreads();

    for(int cb=0; cb<3; cb++){
        int c2 = cb*128 + col;
        float a2[8][4];
        { float4 b = *(const float4*)&b2[c2];
#pragma unroll
          for(int r=0;r<8;r++){a2[r][0]=b.x;a2[r][1]=b.y;a2[r][2]=b.z;a2[r][3]=b.w;} }
        for(int k=0;k<128;k++){
            float4 w  = *(const float4*)&W2[(size_t)k*384 + c2];
            float4 a0 = *(const float4*)&smem[k*68 + ty*8];
            float4 a1 = *(const float4*)&smem[k*68 + ty*8 + 4];
            fma8x4(a2, a0, a1, w);
        }
#pragma unroll
        for(int r=0;r<8;r++){
            int n = n0 + ty*8 + r;
            if(n < N_NODES){
                float4 o = make_float4(a2[r][0],a2[r][1],a2[r][2],a2[r][3]);
                *(float4*)&x[(size_t)n*384 + c2] = o;
            }
        }
    }
}

// ---------------- edge gather + segment sum (one block per sender node) ----------------
// 256 threads = two 128-lane halves processing interleaved edges.
// Edge indices (eord, recv) preloaded cooperatively into LDS: no serial pointer chase.
// Wij/dir are touched exactly once -> nontemporal loads (keep L2/L3 for x/v gathers).
__global__ __launch_bounds__(256) void edge_kernel(
    const float* __restrict__ s, const float* __restrict__ v,
    const float* __restrict__ dir, const float* __restrict__ Wij,
    const int* __restrict__ recv, const int* __restrict__ offs,
    const int* __restrict__ eord, const float* __restrict__ x,
    float* __restrict__ out)
{
    __shared__ int sE[256];
    __shared__ int sR[256];
    __shared__ float red[4*128];
    int n = blockIdx.x;
    int t = threadIdx.x;
    int h = t & 127, sub = t >> 7;
    int start = offs[n], end = offs[n+1];
    float ds=0.f, dv0=0.f, dv1=0.f, dv2=0.f;

    for(int base = start; base < end; base += 256){
        int cnt = min(end - base, 256);
        __syncthreads();                         // protect sE/sR reuse across chunks
        if(t < cnt) sE[t] = eord[base + t];
        __syncthreads();
        if(t < cnt) sR[t] = recv[sE[t]];
        __syncthreads();
        for(int j = sub; j < cnt; j += 2){
            int e = sE[j], r = sR[j];
            const float* wr = &Wij[(size_t)e*384];
            float w0 = __builtin_nontemporal_load(wr + h);
            float w1 = __builtin_nontemporal_load(wr + 128 + h);
            float w2 = __builtin_nontemporal_load(wr + 256 + h);
            float d0 = __builtin_nontemporal_load(dir + (size_t)e*3 + 0);
            float d1 = __builtin_nontemporal_load(dir + (size_t)e*3 + 1);
            float d2 = __builtin_nontemporal_load(dir + (size_t)e*3 + 2);
            const float* xr = &x[(size_t)r*384];
            float x0 = xr[h], x1 = xr[128+h], x2 = xr[256+h];
            const float* vr = &v[(size_t)r*384];
            float vv0 = vr[h], vv1 = vr[128+h], vv2 = vr[256+h];
            ds += w0*x0;
            float a = w1*x1, b = w2*x2;
            dv0 += a*d0 + b*vv0;
            dv1 += a*d1 + b*vv1;
            dv2 += a*d2 + b*vv2;
        }
    }

    if(sub == 1){
        red[h] = ds; red[128+h] = dv0; red[256+h] = dv1; red[384+h] = dv2;
    }
    __syncthreads();
    if(sub == 0){
        ds  += red[h];
        dv0 += red[128+h];
        dv1 += red[256+h];
        dv2 += red[384+h];
        out[(size_t)n*128 + h] = s[(size_t)n*128 + h] + clip100(ds);
        float* ov = out + (size_t)N_NODES*128;
        ov[((size_t)n*3+0)*128 + h] = v[((size_t)n*3+0)*128 + h] + clip100(dv0);
        ov[((size_t)n*3+1)*128 + h] = v[((size_t)n*3+1)*128 + h] + clip100(dv1);
        ov[((size_t)n*3+2)*128 + h] = v[((size_t)n*3+2)*128 + h] + clip100(dv2);
    }
}

// ---------------- vw = v_mid @ Wv ; v_l out; v_norm, vdot ----------------
// 16 nodes (48 rows) per block, 256 threads. W staged in LDS (k-chunks of 32).
// LDS peak: vw tile 48*256 floats = 48KB (GEMM stage uses a sub-region).
__global__ __launch_bounds__(256) void vw_kernel(
    const float* __restrict__ dout, const float* __restrict__ Wv,
    float* __restrict__ vl, float* __restrict__ vnorm, float* __restrict__ vdot)
{
    __shared__ float smem[48*256];
    float* aC = smem;                 // [32][52] = 1664 floats
    float* wC = smem + 1664;          // [32][256] = 8192 floats
    const float* vm_g = dout + (size_t)N_NODES*128;
    int t = threadIdx.x, tx = t&63, ty = t>>6;   // tx: 64 col-groups of 4; ty: 4 row-groups of 12
    int r0 = blockIdx.x*48;                       // row = n*3+c; 48 % 3 == 0 -> node aligned

    float acc[12][4] = {};
    for(int kc=0; kc<4; kc++){
        __syncthreads();
        for(int f=t; f<48*32; f+=256){
            int row = f>>5, kk = f&31;
            int gr = r0 + row;
            aC[kk*52+row] = (gr < N_NODES*3)? vm_g[(size_t)gr*128 + kc*32 + kk] : 0.0f;
        }
        for(int f=t; f<32*256; f+=256){
            int kk = f>>8, c = f&255;
            wC[kk*256+c] = Wv[(size_t)(kc*32+kk)*256 + c];
        }
        __syncthreads();
        for(int kk=0;kk<32;kk++){
            float4 w  = *(const float4*)&wC[kk*256 + tx*4];
            float4 a0 = *(const float4*)&aC[kk*52 + ty*12];
            float4 a1 = *(const float4*)&aC[kk*52 + ty*12 + 4];
            float4 a2 = *(const float4*)&aC[kk*52 + ty*12 + 8];
            float av[12] = {a0.x,a0.y,a0.z,a0.w,a1.x,a1.y,a1.z,a1.w,a2.x,a2.y,a2.z,a2.w};
            float wv[4] = {w.x,w.y,w.z,w.w};
#pragma unroll
            for(int r=0;r<12;r++)
#pragma unroll
                for(int c=0;c<4;c++) acc[r][c] += av[r]*wv[c];
        }
    }
    __syncthreads();
#pragma unroll
    for(int r=0;r<12;r++){
        float4 o = make_float4(acc[r][0],acc[r][1],acc[r][2],acc[r][3]);
        *(float4*)&smem[(ty*12+r)*256 + tx*4] = o;
    }
    __syncthreads();
    // v_l (cols 0..127) -> global
    for(int f=t; f<48*128; f+=256){
        int row = f>>7, c = f&127;
        int gr = r0 + row;
        if(gr < N_NODES*3) vl[(size_t)gr*128 + c] = smem[row*256 + c];
    }
    // v_norm / vdot over c=0..2
    for(int f=t; f<16*128; f+=256){
        int nl = f>>7, hc = f&127;
        int n = r0/3 + nl;
        if(n < N_NODES){
            float l0 = smem[(nl*3+0)*256 + hc], l1 = smem[(nl*3+1)*256 + hc], l2 = smem[(nl*3+2)*256 + hc];
            float q0 = smem[(nl*3+0)*256 + 128 + hc], q1 = smem[(nl*3+1)*256 + 128 + hc], q2 = smem[(nl*3+2)*256 + 128 + hc];
            vnorm[(size_t)n*128 + hc] = sqrtf(q0*q0 + q1*q1 + q2*q2 + EPSV);
            vdot [(size_t)n*128 + hc] = l0*q0 + l1*q1 + l2*q2;
        }
    }
}

// ---------------- update MLP + final outputs ----------------
// 64 nodes/block, 256 threads. LDS: hT[128][68] (34.8KB) + aC[64][68] (17.4KB) = 52.2KB.
__global__ __launch_bounds__(256) void update_kernel(
    const float* __restrict__ vnorm, const float* __restrict__ vdot,
    const float* __restrict__ vl,
    const float* __restrict__ Wm1, const float* __restrict__ bm1,
    const float* __restrict__ Wm2, const float* __restrict__ bm2,
    float* __restrict__ dout)
{
    __shared__ float hT[128*68];
    __shared__ float aC[64*68];
    int t = threadIdx.x, tx = t&31, ty = t>>5;
    int n0 = blockIdx.x*64;
    int col = tx*4;
    float* s_g = dout;
    float* v_g = dout + (size_t)N_NODES*128;

    float acc[8][4];
    { float4 b = *(const float4*)&bm1[col];
#pragma unroll
      for(int r=0;r<8;r++){acc[r][0]=b.x;acc[r][1]=b.y;acc[r][2]=b.z;acc[r][3]=b.w;} }

    for(int kc=0; kc<4; kc++){
        int kbase = kc*64;
        __syncthreads();
        for(int f=t; f<64*64; f+=256){
            int i = f>>6, kk = f&63;
            int n = n0+i;
            float val = 0.f;
            if(n < N_NODES){
                int kg = kbase + kk;
                val = (kg < 128)? s_g[(size_t)n*128 + kg] : vnorm[(size_t)n*128 + kg-128];
            }
            aC[kk*68+i] = val;
        }
        __syncthreads();
        for(int kk=0;kk<64;kk++){
            int k = kbase + kk;
            float4 w  = *(const float4*)&Wm1[(size_t)k*128 + col];
            float4 a0 = *(const float4*)&aC[kk*68 + ty*8];
            float4 a1 = *(const float4*)&aC[kk*68 + ty*8 + 4];
            fma8x4(acc, a0, a1, w);
        }
    }
    __syncthreads();
#pragma unroll
    for(int c=0;c<4;c++)
#pragma unroll
        for(int r=0;r<8;r++) hT[(col+c)*68 + ty*8 + r] = silu_(acc[r][c]);
    __syncthreads();

    float ds2[8][4];
    for(int cb=0; cb<3; cb++){
        float a2[8][4];
        { float4 b = *(const float4*)&bm2[cb*128+col];
#pragma unroll
          for(int r=0;r<8;r++){a2[r][0]=b.x;a2[r][1]=b.y;a2[r][2]=b.z;a2[r][3]=b.w;} }
        for(int k=0;k<128;k++){
            float4 w  = *(const float4*)&Wm2[(size_t)k*384 + cb*128 + col];
            float4 a0 = *(const float4*)&hT[k*68 + ty*8];
            float4 a1 = *(const float4*)&hT[k*68 + ty*8 + 4];
            fma8x4(a2, a0, a1, w);
        }
        if(cb==0){
#pragma unroll
            for(int r=0;r<8;r++)
#pragma unroll
                for(int c=0;c<4;c++) ds2[r][c] = a2[r][c];
        } else if(cb==1){
#pragma unroll
            for(int r=0;r<8;r++){
                int n = n0 + ty*8 + r;
                if(n < N_NODES){
#pragma unroll
                    for(int c3=0;c3<3;c3++){
                        size_t idx = ((size_t)n*3 + c3)*128 + col;
                        float4 vlv = *(const float4*)&vl[idx];
                        float4 vmv = *(const float4*)&v_g[idx];
                        float4 o;
                        o.x = vmv.x + clip100(vlv.x * a2[r][0]);
                        o.y = vmv.y + clip100(vlv.y * a2[r][1]);
                        o.z = vmv.z + clip100(vlv.z * a2[r][2]);
                        o.w = vmv.w + clip100(vlv.w * a2[r][3]);
                        *(float4*)&v_g[idx] = o;
                    }
                }
            }
        } else {
#pragma unroll
            for(int r=0;r<8;r++){
                int n = n0 + ty*8 + r;
                if(n < N_NODES){
                    float4 vd = *(const float4*)&vdot[(size_t)n*128 + col];
                    float4 sm = *(const float4*)&s_g[(size_t)n*128 + col];
                    float4 o;
                    o.x = sm.x + clip100(ds2[r][0] + a2[r][0]*vd.x);
                    o.y = sm.y + clip100(ds2[r][1] + a2[r][1]*vd.y);
                    o.z = sm.z + clip100(ds2[r][2] + a2[r][2]*vd.z);
                    o.w = sm.w + clip100(ds2[r][3] + a2[r][3]*vd.w);
                    *(float4*)&s_g[(size_t)n*128 + col] = o;
                }
            }
        }
    }
}

extern "C" void kernel_launch(void* const* d_in, const int* in_sizes, int n_in,
                              void* d_out, int out_size, void* d_ws, size_t ws_size,
                              hipStream_t stream)
{
    const float* s    = (const float*)d_in[0];
    const float* v    = (const float*)d_in[1];
    const float* dir  = (const float*)d_in[2];
    const float* Wij  = (const float*)d_in[3];
    const int* senders   = (const int*)d_in[4];
    const int* receivers = (const int*)d_in[5];
    const float* W1  = (const float*)d_in[6];
    const float* b1  = (const float*)d_in[7];
    const float* W2  = (const float*)d_in[8];
    const float* b2  = (const float*)d_in[9];
    const float* Wm1 = (const float*)d_in[10];
    const float* bm1 = (const float*)d_in[11];
    const float* Wm2 = (const float*)d_in[12];
    const float* bm2 = (const float*)d_in[13];
    const float* Wv  = (const float*)d_in[14];
    float* out = (float*)d_out;

    float* ws = (float*)d_ws;
    float* x_ws     = ws;                                  // N*384 floats; reused as v_l
    float* vnorm_ws = ws + (size_t)N_NODES*384;            // N*128
    float* vdot_ws  = vnorm_ws + (size_t)N_NODES*128;      // N*128
    int* offs   = (int*)(vdot_ws + (size_t)N_NODES*128);   // N+1
    int* cursor = offs + (N_NODES+1);                      // N
    int* eord   = cursor + N_NODES;                        // E

    hipMemsetAsync(cursor, 0, N_NODES*sizeof(int), stream);
    count_kernel  <<<(N_EDGES+255)/256, 256, 0, stream>>>(senders, cursor);
    scan_kernel   <<<1, 1024, 0, stream>>>(cursor, offs);
    scatter_kernel<<<(N_EDGES+255)/256, 256, 0, stream>>>(senders, cursor, eord);
    mlp_x_kernel  <<<(N_NODES+63)/64, 256, 0, stream>>>(s, W1, b1, W2, b2, x_ws);
    edge_kernel   <<<N_NODES, 256, 0, stream>>>(s, v, dir, Wij, receivers, offs, eord, x_ws, out);
    vw_kernel     <<<(N_NODES+15)/16, 256, 0, stream>>>(out, Wv, x_ws, vnorm_ws, vdot_ws);
    update_kernel <<<(N_NODES+63)/64, 256, 0, stream>>>(vnorm_ws, vdot_ws, x_ws, Wm1, bm1, Wm2, bm2, out);
}

// Round 2
// 2522.826 us; speedup vs baseline: 1.0613x; 1.0423x over previous
//
#include <hip/hip_runtime.h>
#include <math.h>

#define N_NODES 50000
#define N_EDGES 800000
#define HDIM 128
#define EPSV 1e-8f

__device__ __forceinline__ float silu_(float x){ return x / (1.0f + __expf(-x)); }
__device__ __forceinline__ float clip100(float x){ return fminf(fmaxf(x, -100.0f), 100.0f); }

// bf16 helpers (RNE)
__device__ __forceinline__ unsigned short f2bf(float f){
    unsigned int u = __float_as_uint(f);
    unsigned int r = (u + 0x7FFFu + ((u >> 16) & 1u)) >> 16;
    return (unsigned short)r;
}
__device__ __forceinline__ float bf2f(unsigned short b){
    return __uint_as_float(((unsigned int)b) << 16);
}
__device__ __forceinline__ unsigned int pack2bf(float lo, float hi){
    return (unsigned int)f2bf(lo) | ((unsigned int)f2bf(hi) << 16);
}

__device__ __forceinline__ void fma8x4(float (&acc)[8][4], const float4& a0, const float4& a1, const float4& w){
    float av[8] = {a0.x,a0.y,a0.z,a0.w,a1.x,a1.y,a1.z,a1.w};
    float wv[4] = {w.x,w.y,w.z,w.w};
#pragma unroll
    for(int r=0;r<8;r++)
#pragma unroll
        for(int c=0;c<4;c++) acc[r][c] += av[r]*wv[c];
}

// ---------------- CSR build ----------------
__global__ void count_kernel(const int* __restrict__ senders, int* __restrict__ cursor){
    int e = blockIdx.x*256 + threadIdx.x;
    if(e < N_EDGES) atomicAdd(&cursor[senders[e]], 1);
}

__global__ __launch_bounds__(1024) void scan_kernel(int* __restrict__ cursor, int* __restrict__ offs){
    __shared__ int lds[1024];
    const int CH = 49;                      // 1024*49 >= 50000
    int t = threadIdx.x;
    int base = t*CH;
    int sum = 0;
    for(int i=0;i<CH;i++){ int idx = base+i; if(idx < N_NODES) sum += cursor[idx]; }
    lds[t] = sum; __syncthreads();
    for(int off=1; off<1024; off<<=1){
        int v = (t>=off)? lds[t-off] : 0;
        __syncthreads();
        lds[t] += v;
        __syncthreads();
    }
    int run = lds[t] - sum;                 // exclusive prefix
    for(int i=0;i<CH;i++){
        int idx = base+i;
        if(idx < N_NODES){
            int c = cursor[idx];
            offs[idx] = run;
            cursor[idx] = run;              // scatter cursor
            run += c;
        }
    }
    if(t==1023) offs[N_NODES] = lds[1023];
}

__global__ void scatter_kernel(const int* __restrict__ senders, int* __restrict__ cursor, int* __restrict__ eord){
    int e = blockIdx.x*256 + threadIdx.x;
    if(e < N_EDGES){
        int pos = atomicAdd(&cursor[senders[e]], 1);
        eord[pos] = e;
    }
}

// ---------------- v -> bf16 copy (gather operand compression) ----------------
// N*384 floats = 19.2M; each thread converts 8.
__global__ __launch_bounds__(256) void cast_v_kernel(const float* __restrict__ v, unsigned int* __restrict__ vb){
    size_t i = (size_t)blockIdx.x*256 + threadIdx.x;     // uint4-granule index (8 floats)
    size_t total = (size_t)N_NODES*384/8;
    if(i < total){
        const float4* src = (const float4*)(v + i*8);
        float4 a = src[0], b = src[1];
        uint4 o;
        o.x = pack2bf(a.x, a.y);
        o.y = pack2bf(a.z, a.w);
        o.z = pack2bf(b.x, b.y);
        o.w = pack2bf(b.z, b.w);
        ((uint4*)vb)[i] = o;
    }
}

// ---------------- x = silu(s@W1+b1)@W2+b2, stored bf16 ----------------
// 64 nodes/block, 256 threads. LDS: sT[128][68] overlaid by hT[128][68]. 34.8KB.
__global__ __launch_bounds__(256) void mlp_x_kernel(
    const float* __restrict__ s, const float* __restrict__ W1, const float* __restrict__ b1,
    const float* __restrict__ W2, const float* __restrict__ b2, unsigned short* __restrict__ xb)
{
    __shared__ float smem[128*68];
    int t = threadIdx.x, tx = t&31, ty = t>>5;
    int n0 = blockIdx.x*64;
    int col = tx*4;

    for(int f=t; f<64*128; f+=256){
        int i = f>>7, k = f&127;
        int n = n0+i;
        smem[k*68+i] = (n<N_NODES)? s[(size_t)n*128+k] : 0.0f;
    }
    __syncthreads();

    float acc[8][4];
    { float4 b = *(const float4*)&b1[col];
#pragma unroll
      for(int r=0;r<8;r++){acc[r][0]=b.x;acc[r][1]=b.y;acc[r][2]=b.z;acc[r][3]=b.w;} }
    for(int k=0;k<128;k++){
        float4 w  = *(const float4*)&W1[k*128+col];
        float4 a0 = *(const float4*)&smem[k*68 + ty*8];
        float4 a1 = *(const float4*)&smem[k*68 + ty*8 + 4];
        fma8x4(acc, a0, a1, w);
    }
    __syncthreads();   // all sT reads done
#pragma unroll
    for(int c=0;c<4;c++)
#pragma unroll
        for(int r=0;r<8;r++) smem[(col+c)*68 + ty*8 + r] = silu_(acc[r][c]);
    __syncthreads();

    for(int cb=0; cb<3; cb++){
        int c2 = cb*128 + col;
        float a2[8][4];
        { float4 b = *(const float4*)&b2[c2];
#pragma unroll
          for(int r=0;r<8;r++){a2[r][0]=b.x;a2[r][1]=b.y;a2[r][2]=b.z;a2[r][3]=b.w;} }
        for(int k=0;k<128;k++){
            float4 w  = *(const float4*)&W2[(size_t)k*384 + c2];
            float4 a0 = *(const float4*)&smem[k*68 + ty*8];
            float4 a1 = *(const float4*)&smem[k*68 + ty*8 + 4];
            fma8x4(a2, a0, a1, w);
        }
#pragma unroll
        for(int r=0;r<8;r++){
            int n = n0 + ty*8 + r;
            if(n < N_NODES){
                ushort4 o;
                o.x = f2bf(a2[r][0]); o.y = f2bf(a2[r][1]);
                o.z = f2bf(a2[r][2]); o.w = f2bf(a2[r][3]);
                *(ushort4*)&xb[(size_t)n*384 + c2] = o;
            }
        }
    }
}

// ---------------- edge gather + segment sum (one block per sender node) ----------------
// 256 threads = two 128-lane halves processing interleaved edges.
// Edge indices preloaded into LDS (no pointer chase). Gathered operands x,v are bf16
// (half the gather bytes); Wij/dir streamed nontemporal; self terms + output fp32.
__global__ __launch_bounds__(256) void edge_kernel(
    const float* __restrict__ s, const float* __restrict__ v,
    const float* __restrict__ dir, const float* __restrict__ Wij,
    const int* __restrict__ recv, const int* __restrict__ offs,
    const int* __restrict__ eord, const unsigned short* __restrict__ xb,
    const unsigned short* __restrict__ vb,
    float* __restrict__ out)
{
    __shared__ int sE[256];
    __shared__ int sR[256];
    __shared__ float red[4*128];
    int n = blockIdx.x;
    int t = threadIdx.x;
    int h = t & 127, sub = t >> 7;
    int start = offs[n], end = offs[n+1];
    float ds=0.f, dv0=0.f, dv1=0.f, dv2=0.f;

    for(int base = start; base < end; base += 256){
        int cnt = min(end - base, 256);
        __syncthreads();                         // protect sE/sR reuse across chunks
        if(t < cnt) sE[t] = eord[base + t];
        __syncthreads();
        if(t < cnt) sR[t] = recv[sE[t]];
        __syncthreads();
        for(int j = sub; j < cnt; j += 2){
            int e = sE[j], r = sR[j];
            const float* wr = &Wij[(size_t)e*384];
            float w0 = __builtin_nontemporal_load(wr + h);
            float w1 = __builtin_nontemporal_load(wr + 128 + h);
            float w2 = __builtin_nontemporal_load(wr + 256 + h);
            float d0 = __builtin_nontemporal_load(dir + (size_t)e*3 + 0);
            float d1 = __builtin_nontemporal_load(dir + (size_t)e*3 + 1);
            float d2 = __builtin_nontemporal_load(dir + (size_t)e*3 + 2);
            const unsigned short* xr = &xb[(size_t)r*384];
            float x0 = bf2f(xr[h]), x1 = bf2f(xr[128+h]), x2 = bf2f(xr[256+h]);
            const unsigned short* vr = &vb[(size_t)r*384];
            float vv0 = bf2f(vr[h]), vv1 = bf2f(vr[128+h]), vv2 = bf2f(vr[256+h]);
            ds += w0*x0;
            float a = w1*x1, b = w2*x2;
            dv0 += a*d0 + b*vv0;
            dv1 += a*d1 + b*vv1;
            dv2 += a*d2 + b*vv2;
        }
    }

    if(sub == 1){
        red[h] = ds; red[128+h] = dv0; red[256+h] = dv1; red[384+h] = dv2;
    }
    __syncthreads();
    if(sub == 0){
        ds  += red[h];
        dv0 += red[128+h];
        dv1 += red[256+h];
        dv2 += red[384+h];
        out[(size_t)n*128 + h] = s[(size_t)n*128 + h] + clip100(ds);
        float* ov = out + (size_t)N_NODES*128;
        ov[((size_t)n*3+0)*128 + h] = v[((size_t)n*3+0)*128 + h] + clip100(dv0);
        ov[((size_t)n*3+1)*128 + h] = v[((size_t)n*3+1)*128 + h] + clip100(dv1);
        ov[((size_t)n*3+2)*128 + h] = v[((size_t)n*3+2)*128 + h] + clip100(dv2);
    }
}

// ---------------- vw = v_mid @ Wv ; v_l out; v_norm, vdot ----------------
// 16 nodes (48 rows) per block, 256 threads. W staged in LDS (k-chunks of 32).
// LDS peak: vw tile 48*256 floats = 48KB (GEMM stage uses a sub-region).
__global__ __launch_bounds__(256) void vw_kernel(
    const float* __restrict__ dout, const float* __restrict__ Wv,
    float* __restrict__ vl, float* __restrict__ vnorm, float* __restrict__ vdot)
{
    __shared__ float smem[48*256];
    float* aC = smem;                 // [32][52] = 1664 floats
    float* wC = smem + 1664;          // [32][256] = 8192 floats
    const float* vm_g = dout + (size_t)N_NODES*128;
    int t = threadIdx.x, tx = t&63, ty = t>>6;   // tx: 64 col-groups of 4; ty: 4 row-groups of 12
    int r0 = blockIdx.x*48;                       // row = n*3+c; 48 % 3 == 0 -> node aligned

    float acc[12][4] = {};
    for(int kc=0; kc<4; kc++){
        __syncthreads();
        for(int f=t; f<48*32; f+=256){
            int row = f>>5, kk = f&31;
            int gr = r0 + row;
            aC[kk*52+row] = (gr < N_NODES*3)? vm_g[(size_t)gr*128 + kc*32 + kk] : 0.0f;
        }
        for(int f=t; f<32*256; f+=256){
            int kk = f>>8, c = f&255;
            wC[kk*256+c] = Wv[(size_t)(kc*32+kk)*256 + c];
        }
        __syncthreads();
        for(int kk=0;kk<32;kk++){
            float4 w  = *(const float4*)&wC[kk*256 + tx*4];
            float4 a0 = *(const float4*)&aC[kk*52 + ty*12];
            float4 a1 = *(const float4*)&aC[kk*52 + ty*12 + 4];
            float4 a2 = *(const float4*)&aC[kk*52 + ty*12 + 8];
            float av[12] = {a0.x,a0.y,a0.z,a0.w,a1.x,a1.y,a1.z,a1.w,a2.x,a2.y,a2.z,a2.w};
            float wv[4] = {w.x,w.y,w.z,w.w};
#pragma unroll
            for(int r=0;r<12;r++)
#pragma unroll
                for(int c=0;c<4;c++) acc[r][c] += av[r]*wv[c];
        }
    }
    __syncthreads();
#pragma unroll
    for(int r=0;r<12;r++){
        float4 o = make_float4(acc[r][0],acc[r][1],acc[r][2],acc[r][3]);
        *(float4*)&smem[(ty*12+r)*256 + tx*4] = o;
    }
    __syncthreads();
    // v_l (cols 0..127) -> global
    for(int f=t; f<48*128; f+=256){
        int row = f>>7, c = f&127;
        int gr = r0 + row;
        if(gr < N_NODES*3) vl[(size_t)gr*128 + c] = smem[row*256 + c];
    }
    // v_norm / vdot over c=0..2
    for(int f=t; f<16*128; f+=256){
        int nl = f>>7, hc = f&127;
        int n = r0/3 + nl;
        if(n < N_NODES){
            float l0 = smem[(nl*3+0)*256 + hc], l1 = smem[(nl*3+1)*256 + hc], l2 = smem[(nl*3+2)*256 + hc];
            float q0 = smem[(nl*3+0)*256 + 128 + hc], q1 = smem[(nl*3+1)*256 + 128 + hc], q2 = smem[(nl*3+2)*256 + 128 + hc];
            vnorm[(size_t)n*128 + hc] = sqrtf(q0*q0 + q1*q1 + q2*q2 + EPSV);
            vdot [(size_t)n*128 + hc] = l0*q0 + l1*q1 + l2*q2;
        }
    }
}

// ---------------- update MLP + final outputs ----------------
// 64 nodes/block, 256 threads. LDS: hT[128][68] (34.8KB) + aC[64][68] (17.4KB) = 52.2KB.
__global__ __launch_bounds__(256) void update_kernel(
    const float* __restrict__ vnorm, const float* __restrict__ vdot,
    const float* __restrict__ vl,
    const float* __restrict__ Wm1, const float* __restrict__ bm1,
    const float* __restrict__ Wm2, const float* __restrict__ bm2,
    float* __restrict__ dout)
{
    __shared__ float hT[128*68];
    __shared__ float aC[64*68];
    int t = threadIdx.x, tx = t&31, ty = t>>5;
    int n0 = blockIdx.x*64;
    int col = tx*4;
    float* s_g = dout;
    float* v_g = dout + (size_t)N_NODES*128;

    float acc[8][4];
    { float4 b = *(const float4*)&bm1[col];
#pragma unroll
      for(int r=0;r<8;r++){acc[r][0]=b.x;acc[r][1]=b.y;acc[r][2]=b.z;acc[r][3]=b.w;} }

    for(int kc=0; kc<4; kc++){
        int kbase = kc*64;
        __syncthreads();
        for(int f=t; f<64*64; f+=256){
            int i = f>>6, kk = f&63;
            int n = n0+i;
            float val = 0.f;
            if(n < N_NODES){
                int kg = kbase + kk;
                val = (kg < 128)? s_g[(size_t)n*128 + kg] : vnorm[(size_t)n*128 + kg-128];
            }
            aC[kk*68+i] = val;
        }
        __syncthreads();
        for(int kk=0;kk<64;kk++){
            int k = kbase + kk;
            float4 w  = *(const float4*)&Wm1[(size_t)k*128 + col];
            float4 a0 = *(const float4*)&aC[kk*68 + ty*8];
            float4 a1 = *(const float4*)&aC[kk*68 + ty*8 + 4];
            fma8x4(acc, a0, a1, w);
        }
    }
    __syncthreads();
#pragma unroll
    for(int c=0;c<4;c++)
#pragma unroll
        for(int r=0;r<8;r++) hT[(col+c)*68 + ty*8 + r] = silu_(acc[r][c]);
    __syncthreads();

    float ds2[8][4];
    for(int cb=0; cb<3; cb++){
        float a2[8][4];
        { float4 b = *(const float4*)&bm2[cb*128+col];
#pragma unroll
          for(int r=0;r<8;r++){a2[r][0]=b.x;a2[r][1]=b.y;a2[r][2]=b.z;a2[r][3]=b.w;} }
        for(int k=0;k<128;k++){
            float4 w  = *(const float4*)&Wm2[(size_t)k*384 + cb*128 + col];
            float4 a0 = *(const float4*)&hT[k*68 + ty*8];
            float4 a1 = *(const float4*)&hT[k*68 + ty*8 + 4];
            fma8x4(a2, a0, a1, w);
        }
        if(cb==0){
#pragma unroll
            for(int r=0;r<8;r++)
#pragma unroll
                for(int c=0;c<4;c++) ds2[r][c] = a2[r][c];
        } else if(cb==1){
#pragma unroll
            for(int r=0;r<8;r++){
                int n = n0 + ty*8 + r;
                if(n < N_NODES){
#pragma unroll
                    for(int c3=0;c3<3;c3++){
                        size_t idx = ((size_t)n*3 + c3)*128 + col;
                        float4 vlv = *(const float4*)&vl[idx];
                        float4 vmv = *(const float4*)&v_g[idx];
                        float4 o;
                        o.x = vmv.x + clip100(vlv.x * a2[r][0]);
                        o.y = vmv.y + clip100(vlv.y * a2[r][1]);
                        o.z = vmv.z + clip100(vlv.z * a2[r][2]);
                        o.w = vmv.w + clip100(vlv.w * a2[r][3]);
                        *(float4*)&v_g[idx] = o;
                    }
                }
            }
        } else {
#pragma unroll
            for(int r=0;r<8;r++){
                int n = n0 + ty*8 + r;
                if(n < N_NODES){
                    float4 vd = *(const float4*)&vdot[(size_t)n*128 + col];
                    float4 sm = *(const float4*)&s_g[(size_t)n*128 + col];
                    float4 o;
                    o.x = sm.x + clip100(ds2[r][0] + a2[r][0]*vd.x);
                    o.y = sm.y + clip100(ds2[r][1] + a2[r][1]*vd.y);
                    o.z = sm.z + clip100(ds2[r][2] + a2[r][2]*vd.z);
                    o.w = sm.w + clip100(ds2[r][3] + a2[r][3]*vd.w);
                    *(float4*)&s_g[(size_t)n*128 + col] = o;
                }
            }
        }
    }
}

extern "C" void kernel_launch(void* const* d_in, const int* in_sizes, int n_in,
                              void* d_out, int out_size, void* d_ws, size_t ws_size,
                              hipStream_t stream)
{
    const float* s    = (const float*)d_in[0];
    const float* v    = (const float*)d_in[1];
    const float* dir  = (const float*)d_in[2];
    const float* Wij  = (const float*)d_in[3];
    const int* senders   = (const int*)d_in[4];
    const int* receivers = (const int*)d_in[5];
    const float* W1  = (const float*)d_in[6];
    const float* b1  = (const float*)d_in[7];
    const float* W2  = (const float*)d_in[8];
    const float* b2  = (const float*)d_in[9];
    const float* Wm1 = (const float*)d_in[10];
    const float* bm1 = (const float*)d_in[11];
    const float* Wm2 = (const float*)d_in[12];
    const float* bm2 = (const float*)d_in[13];
    const float* Wv  = (const float*)d_in[14];
    float* out = (float*)d_out;

    unsigned short* xb = (unsigned short*)d_ws;                 // N*384 bf16
    unsigned short* vb = xb + (size_t)N_NODES*384;              // N*384 bf16
    float* vl_ws    = (float*)(vb + (size_t)N_NODES*384);       // N*384 f32
    float* vnorm_ws = vl_ws + (size_t)N_NODES*384;              // N*128
    float* vdot_ws  = vnorm_ws + (size_t)N_NODES*128;           // N*128
    int* offs   = (int*)(vdot_ws + (size_t)N_NODES*128);        // N+1
    int* cursor = offs + (N_NODES+1);                           // N
    int* eord   = cursor + N_NODES;                             // E

    hipMemsetAsync(cursor, 0, N_NODES*sizeof(int), stream);
    count_kernel  <<<(N_EDGES+255)/256, 256, 0, stream>>>(senders, cursor);
    scan_kernel   <<<1, 1024, 0, stream>>>(cursor, offs);
    scatter_kernel<<<(N_EDGES+255)/256, 256, 0, stream>>>(senders, cursor, eord);
    cast_v_kernel <<<((N_NODES*384/8)+255)/256, 256, 0, stream>>>(v, (unsigned int*)vb);
    mlp_x_kernel  <<<(N_NODES+63)/64, 256, 0, stream>>>(s, W1, b1, W2, b2, xb);
    edge_kernel   <<<N_NODES, 256, 0, stream>>>(s, v, dir, Wij, receivers, offs, eord, xb, vb, out);
    vw_kernel     <<<(N_NODES+15)/16, 256, 0, stream>>>(out, Wv, vl_ws, vnorm_ws, vdot_ws);
    update_kernel <<<(N_NODES+63)/64, 256, 0, stream>>>(vnorm_ws, vdot_ws, vl_ws, Wm1, bm1, Wm2, bm2, out);
}